// Round 1
// 92.957 us; speedup vs baseline: 1.0966x; 1.0966x over previous
//
#include <hip/hip_runtime.h>
#include <stdint.h>

#define BATCH   2048
#define INDIM   512
#define OUTDIM  512
#define SDIM    8
#define KTOT    4096      // 8 slices * 512 (no padding, no bias rows)
#define SPLITK  4

typedef __attribute__((ext_vector_type(4))) float  f32x4;
typedef __attribute__((ext_vector_type(8))) __bf16 bf16x8;
typedef __attribute__((ext_vector_type(8))) unsigned short u16x8;

__device__ __forceinline__ unsigned short f2bf(float x) {
  unsigned int u = __float_as_uint(x);
  u += 0x7fffu + ((u >> 16) & 1u);      // round-to-nearest-even
  return (unsigned short)(u >> 16);
}

__device__ __forceinline__ void llds16(const void* g, void* s) {
  __builtin_amdgcn_global_load_lds(
      (__attribute__((address_space(1))) void*)g,
      (__attribute__((address_space(3))) void*)s, 16, 0, 0);
}

__device__ __forceinline__ void mkbasis(float t, float* bs) {
  bs[0] = 1.0f; bs[1] = t; bs[2] = t * t; bs[3] = bs[2] * t;
  const float kn[4] = {0.2f, 0.4f, 0.6f, 0.8f};
#pragma unroll
  for (int c = 0; c < 4; ++c) {
    float d = fmaxf(t - kn[c], 0.0f);
    bs[4 + c] = d * d * d;
  }
}

// ---------------------------------------------------------------------------
// prep:
//   blocks [   0, 512): Bt[n][k] = bf16(W[k*512+n])  (transpose-convert, k<4096)
//   blocks [ 512,1024): Fbf[b][i] = bf16(inp[b][1+i]); basis table (f32)
//   blocks [1024,2048): out[b][o] = sum_s basis[b][s]*b_wts[s][o]  (replaces memset)
// ---------------------------------------------------------------------------
__global__ __launch_bounds__(256) void prep_kernel(
    const float* __restrict__ inp, const float* __restrict__ W,
    const float* __restrict__ bwts, unsigned short* __restrict__ Fbf,
    unsigned short* __restrict__ Btf, float* __restrict__ Bas,
    float* __restrict__ out) {
  const int tid = threadIdx.x;
  const int bx  = blockIdx.x;
  if (bx < 512) {
    // ---- W transpose-convert: 64k x 64n tile ----
    const int kt = bx >> 3, ntile = bx & 7;
    const int k0 = kt * 64, n0 = ntile * 64;
    __shared__ float Ts[64][65];           // [n_local][k_local], padded
#pragma unroll
    for (int p = 0; p < 4; ++p) {
      const int r  = (tid >> 4) + p * 16;  // k-local
      const int c4 = (tid & 15) * 4;       // n-local
      float4 v = *(const float4*)&W[(size_t)(k0 + r) * 512 + n0 + c4];
      Ts[c4 + 0][r] = v.x; Ts[c4 + 1][r] = v.y;
      Ts[c4 + 2][r] = v.z; Ts[c4 + 3][r] = v.w;
    }
    __syncthreads();
    const int nl  = tid >> 2;              // 0..63
    const int kcc = (tid & 3) * 16;        // 0,16,32,48
    u16x8 o0, o1;
#pragma unroll
    for (int q = 0; q < 8; ++q) {
      o0[q] = f2bf(Ts[nl][kcc + q]);
      o1[q] = f2bf(Ts[nl][kcc + 8 + q]);
    }
    unsigned short* dst = Btf + (size_t)(n0 + nl) * KTOT + k0 + kcc;
    *(u16x8*)dst = o0;
    *(u16x8*)(dst + 8) = o1;
  } else if (bx < 1024) {
    // ---- feature convert (4 rows per block) + basis table ----
    const int b0   = (bx - 512) * 4;
    const int b    = b0 + (tid >> 6);
    const int i0   = (tid & 63) * 8;
    const float* row = inp + (size_t)b * (INDIM + 1);
    u16x8 o;
#pragma unroll
    for (int q = 0; q < 8; ++q) o[q] = f2bf(row[1 + i0 + q]);
    *(u16x8*)(Fbf + (size_t)b * INDIM + i0) = o;
    if (tid < 4) {
      const int bb = b0 + tid;
      float t = inp[(size_t)bb * (INDIM + 1)];
      float bs[8]; mkbasis(t, bs);
      f32x4 lo = {bs[0], bs[1], bs[2], bs[3]};
      f32x4 hi = {bs[4], bs[5], bs[6], bs[7]};
      *(f32x4*)(Bas + (size_t)bb * 8)     = lo;
      *(f32x4*)(Bas + (size_t)bb * 8 + 4) = hi;
    }
  } else {
    // ---- bias init: out = basis @ b_wts (2 rows per block) ----
    const int bb = (bx - 1024) * 2 + (tid >> 7);
    const int o0 = (tid & 127) * 4;
    float t = inp[(size_t)bb * (INDIM + 1)];
    float bs[8]; mkbasis(t, bs);
    float4 a = make_float4(0.f, 0.f, 0.f, 0.f);
#pragma unroll
    for (int s = 0; s < 8; ++s) {
      float4 wv = *(const float4*)&bwts[s * OUTDIM + o0];
      a.x += bs[s] * wv.x; a.y += bs[s] * wv.y;
      a.z += bs[s] * wv.z; a.w += bs[s] * wv.w;
    }
    *(float4*)&out[(size_t)bb * OUTDIM + o0] = a;
  }
}

// ---------------------------------------------------------------------------
// GEMM: out += sum_s basis[:,s] * (F(2048x512) @ Wk[s](512x512))
// 64x64 tile, BK=64, 4 waves (32x32 quadrants), split-K over s-pairs (4 blocks).
// A-operand is the UNSCALED F; basis applied as exact f32 accumulator scale
// once per s-slice (C/D row = (lane>>4)*4 + reg, verified m89/m91).
// LDS staged via global_load_lds(16B), XOR swizzle on the GLOBAL source chunk.
// ---------------------------------------------------------------------------
__global__ __launch_bounds__(256, 4) void gemm_kernel(
    const unsigned short* __restrict__ Fbf,
    const unsigned short* __restrict__ Btf,
    const float* __restrict__ Bas,
    float* __restrict__ out) {
  const int tid  = threadIdx.x;
  const int kc   = blockIdx.x & (SPLITK - 1);
  const int tile = blockIdx.x >> 2;
  const int nt = tile & 7, mt = tile >> 3;
  const int m0 = mt * 64, n0 = nt * 64;
  const int l = tid & 63, w = tid >> 6;
  const int wm = w >> 1, wn = w & 1;
  const int quad = l >> 4, lr = l & 15;

  __shared__ __align__(16) unsigned short As[64 * 64];
  __shared__ __align__(16) unsigned short Bs[64 * 64];

  f32x4 m00 = {}, m01 = {}, m10 = {}, m11 = {};

  // staging: thread t -> LDS byte offset w*1024 + lane*16 (contiguous).
  // swizzle picks WHICH global 16B chunk lands there: lc = pc ^ (sr&7).
  const int sr = tid >> 3, pc = tid & 7;
  const int lc = pc ^ (sr & 7);
  const unsigned short* Ag = Fbf + (size_t)(m0 + sr) * INDIM + lc * 8;
  const unsigned short* Bg = Btf + (size_t)(n0 + sr) * KTOT + lc * 8;
  unsigned short* AsW = &As[sr * 64 + pc * 8];
  unsigned short* BsW = &Bs[sr * 64 + pc * 8];

  // fragment read offsets; logical chunk q of row r lives at q ^ (r&7)
  const int sx  = lr & 7;
  const int ar  = (wm * 32 + lr) * 64;
  const int br  = (wn * 32 + lr) * 64;
  const int c0  = ((0 + quad) ^ sx) * 8;   // ks = 0
  const int c1  = ((4 + quad) ^ sx) * 8;   // ks = 1

  const float* bp = Bas + (size_t)(m0 + wm * 32 + quad * 4) * 8;

#pragma unroll
  for (int sl = 0; sl < 2; ++sl) {
    const int s = kc * 2 + sl;
    const unsigned short* Bk = Bg + (size_t)s * 512;
    f32x4 p00 = {}, p01 = {}, p10 = {}, p11 = {};
    for (int ib = 0; ib < 8; ++ib) {
      const int ka = ib * 64;
      llds16(Ag + ka,               AsW);
      llds16(Ag + ka + 32 * INDIM,  AsW + 32 * 64);
      llds16(Bk + ka,               BsW);
      llds16(Bk + ka + 32 * KTOT,   BsW + 32 * 64);
      __syncthreads();

      bf16x8 a00 = *(const bf16x8*)&As[ar + c0];
      bf16x8 a10 = *(const bf16x8*)&As[ar + 1024 + c0];
      bf16x8 b00 = *(const bf16x8*)&Bs[br + c0];
      bf16x8 b10 = *(const bf16x8*)&Bs[br + 1024 + c0];
      bf16x8 a01 = *(const bf16x8*)&As[ar + c1];
      bf16x8 a11 = *(const bf16x8*)&As[ar + 1024 + c1];
      bf16x8 b01 = *(const bf16x8*)&Bs[br + c1];
      bf16x8 b11 = *(const bf16x8*)&Bs[br + 1024 + c1];

      p00 = __builtin_amdgcn_mfma_f32_16x16x32_bf16(a00, b00, p00, 0, 0, 0);
      p01 = __builtin_amdgcn_mfma_f32_16x16x32_bf16(a00, b10, p01, 0, 0, 0);
      p10 = __builtin_amdgcn_mfma_f32_16x16x32_bf16(a10, b00, p10, 0, 0, 0);
      p11 = __builtin_amdgcn_mfma_f32_16x16x32_bf16(a10, b10, p11, 0, 0, 0);
      p00 = __builtin_amdgcn_mfma_f32_16x16x32_bf16(a01, b01, p00, 0, 0, 0);
      p01 = __builtin_amdgcn_mfma_f32_16x16x32_bf16(a01, b11, p01, 0, 0, 0);
      p10 = __builtin_amdgcn_mfma_f32_16x16x32_bf16(a11, b01, p10, 0, 0, 0);
      p11 = __builtin_amdgcn_mfma_f32_16x16x32_bf16(a11, b11, p11, 0, 0, 0);

      __syncthreads();
    }
    // scale this s-slice's partial by basis[row][s] (f32, exact) into master
#pragma unroll
    for (int r = 0; r < 4; ++r) {
      const float f0 = bp[r * 8 + s];          // rows quad*4+r       (acc00/01)
      const float f1 = bp[(16 + r) * 8 + s];   // rows quad*4+r+16    (acc10/11)
      m00[r] += p00[r] * f0; m01[r] += p01[r] * f0;
      m10[r] += p10[r] * f1; m11[r] += p11[r] * f1;
    }
  }

  // C/D layout: col = lane&15, row = (lane>>4)*4 + reg
  const int col = n0 + wn * 32 + lr;
  const int row = m0 + wm * 32 + quad * 4;
  float* o00 = out + (size_t)row * OUTDIM + col;
#pragma unroll
  for (int r = 0; r < 4; ++r) {
    unsafeAtomicAdd(o00 + (size_t)r * OUTDIM,             m00[r]);
    unsafeAtomicAdd(o00 + (size_t)r * OUTDIM + 16,        m01[r]);
    unsafeAtomicAdd(o00 + (size_t)(16 + r) * OUTDIM,      m10[r]);
    unsafeAtomicAdd(o00 + (size_t)(16 + r) * OUTDIM + 16, m11[r]);
  }
}

extern "C" void kernel_launch(void* const* d_in, const int* in_sizes, int n_in,
                              void* d_out, int out_size, void* d_ws, size_t ws_size,
                              hipStream_t stream) {
  const float* inp  = (const float*)d_in[0];   // (2048, 513)
  const float* W    = (const float*)d_in[1];   // (8, 262144) == (4096, 512) row-major
  const float* bwts = (const float*)d_in[2];   // (8, 512)
  float* out = (float*)d_out;

  unsigned short* Fbf = (unsigned short*)d_ws;                  // 2048*512 bf16 = 2 MB
  unsigned short* Btf = Fbf + (size_t)BATCH * INDIM;            // 512*4096 bf16 = 4 MB
  float*          Bas = (float*)(Btf + (size_t)OUTDIM * KTOT);  // 2048*8 f32 = 64 KB

  prep_kernel<<<2048, 256, 0, stream>>>(inp, W, bwts, Fbf, Btf, Bas, out);
  gemm_kernel<<<(BATCH / 64) * (OUTDIM / 64) * SPLITK, 256, 0, stream>>>(Fbf, Btf, Bas, out);
}